// Round 12
// baseline (487.131 us; speedup 1.0000x reference)
//
#include <hip/hip_runtime.h>
#include <hip/hip_bf16.h>

#define N_ROWS 262144
#define DDIM   256
#define PROTO  512
#define BM     64
#define TPB    8      // tiles per block
#define RGS    512    // row groups (blocks per cc)
#define NBLK   1024   // RGS * 2 cc

typedef __bf16 bf16x8 __attribute__((ext_vector_type(8)));
typedef float  f32x4  __attribute__((ext_vector_type(4)));

// ---------------- prep: prototypes fp32 -> bf16 in MFMA-fragment order, p2 ----------------
// idx = (p>>4)*4096 + (k>>5)*512 + ((((k>>3)&3)*16) + (p&15))*8 + (k&7)
__global__ void prep_proto(const float* __restrict__ Pm,
                           unsigned short* __restrict__ PBf,
                           float* __restrict__ P2) {
  int p = blockIdx.x;     // 512
  int k = threadIdx.x;    // 256
  float v = Pm[p * DDIM + k];
  int idx = (p >> 4) * 4096 + (k >> 5) * 512 + ((((k >> 3) & 3) * 16) + (p & 15)) * 8 + (k & 7);
  ((__bf16*)PBf)[idx] = (__bf16)v;
  float sq = v * v;
  #pragma unroll
  for (int m = 1; m < 64; m <<= 1) sq += __shfl_xor(sq, m);
  __shared__ float ws4[4];
  if ((k & 63) == 0) ws4[k >> 6] = sq;
  __syncthreads();
  if (k == 0) P2[p] = (ws4[0] + ws4[1]) + (ws4[2] + ws4[3]);
}

// ---------------- main: persistent 8-tile blocks, double-buffered A, T14 prefetch ----------
// 1024 blocks x 256 threads; __launch_bounds__(256,2) -> 256 regs/wave, 2 blocks/CU (LDS 67KB).
// rg = ((bid>>4)<<3)|(bid&7), cc = (bid>>3)&1 (cc-siblings share an XCD for Z L2 reuse).
// Block covers rows [rg*512, rg*512+512) as 8 tiles of 64, cols [cc*256, +256).
// Per tile: issue next tile's 16 global loads -> K-loop(buf cur) -> epilogue -> barrier ->
// convert regs -> buf nxt -> barrier. Staging latency hides under the K-loop.
__global__ __launch_bounds__(256, 2)
void proto_main(const float* __restrict__ Z, const unsigned short* __restrict__ PBf,
                const float* __restrict__ P2, float* __restrict__ colpart,
                float* __restrict__ rowminpart) {
  __shared__ __align__(16) unsigned short A0[BM * 256];   // 32768 B, swizzled
  __shared__ __align__(16) unsigned short A1[BM * 256];   // 32768 B
  __shared__ float z2s[2][BM];
  __shared__ float rowred[BM * 4];

  const int t   = threadIdx.x;
  const int w   = t >> 6;   // wave 0..3
  const int l   = t & 63;
  const int l15 = l & 15;
  const int lg  = l >> 4;   // 0..3

  const int bid = blockIdx.x;
  const int rg  = ((bid >> 4) << 3) | (bid & 7);  // row group 0..511
  const int cc  = (bid >> 3) & 1;                 // col chunk 0..1

  const int srow = t >> 2;  // staging: 4 threads per row
  const int sc4  = t & 3;

  float p2r[4];
  #pragma unroll
  for (int j = 0; j < 4; ++j) p2r[j] = P2[cc * 256 + w * 64 + j * 16 + l15];

  float colmin[4] = {3.4e38f, 3.4e38f, 3.4e38f, 3.4e38f};  // accumulated across tiles

  const unsigned short* PBw = PBf + (size_t)(cc * 16 + w * 4) * 4096 + l * 8;

  // ---- prologue: load + convert tile 0 into A0 ----
  float4 za[16];
  {
    const float4* Zv = (const float4*)Z + ((size_t)rg * TPB * BM + srow) * (DDIM / 4);
    #pragma unroll
    for (int m = 0; m < 8; ++m) {
      za[2 * m]     = Zv[(sc4 + m * 4) * 2];
      za[2 * m + 1] = Zv[(sc4 + m * 4) * 2 + 1];
    }
    float zacc = 0.f;
    #pragma unroll
    for (int m = 0; m < 8; ++m) {
      float4 a0 = za[2 * m], a1 = za[2 * m + 1];
      zacc += a0.x*a0.x + a0.y*a0.y + a0.z*a0.z + a0.w*a0.w
            + a1.x*a1.x + a1.y*a1.y + a1.z*a1.z + a1.w*a1.w;
      bf16x8 pk;
      pk[0] = (__bf16)a0.x; pk[1] = (__bf16)a0.y; pk[2] = (__bf16)a0.z; pk[3] = (__bf16)a0.w;
      pk[4] = (__bf16)a1.x; pk[5] = (__bf16)a1.y; pk[6] = (__bf16)a1.z; pk[7] = (__bf16)a1.w;
      int slot = (sc4 + m * 4) ^ (srow & 7);
      *(bf16x8*)&A0[srow * 256 + slot * 8] = pk;
    }
    zacc += __shfl_xor(zacc, 1);
    zacc += __shfl_xor(zacc, 2);
    if (sc4 == 0) z2s[0][srow] = zacc;
  }
  __syncthreads();

  for (int tt = 0; tt < TPB; ++tt) {
    const int cur = tt & 1;
    const unsigned short* Ab = cur ? A1 : A0;
    const size_t row0 = (size_t)(rg * TPB + tt) * BM;

    // ---- T14: issue next tile's global loads (consumed after the K-loop) ----
    if (tt < TPB - 1) {
      const float4* Zv = (const float4*)Z + (row0 + BM + srow) * (DDIM / 4);
      #pragma unroll
      for (int m = 0; m < 8; ++m) {
        za[2 * m]     = Zv[(sc4 + m * 4) * 2];
        za[2 * m + 1] = Zv[(sc4 + m * 4) * 2 + 1];
      }
    }

    // ---- K loop: 8 steps of BK=32; A from swizzled LDS, B 1-deep prefetch from L2 ----
    f32x4 acc[4][4];
    #pragma unroll
    for (int i = 0; i < 4; ++i)
      #pragma unroll
      for (int j = 0; j < 4; ++j)
        acc[i][j] = (f32x4){0.f, 0.f, 0.f, 0.f};

    bf16x8 bgn[4];
    #pragma unroll
    for (int j = 0; j < 4; ++j)
      bgn[j] = *(const bf16x8*)&PBw[(size_t)(j * 8) * 512];
    #pragma unroll
    for (int ks = 0; ks < 8; ++ks) {
      bf16x8 bgc[4];
      #pragma unroll
      for (int j = 0; j < 4; ++j) bgc[j] = bgn[j];
      if (ks < 7) {
        #pragma unroll
        for (int j = 0; j < 4; ++j)
          bgn[j] = *(const bf16x8*)&PBw[(size_t)(j * 8 + ks + 1) * 512];
      }
      __builtin_amdgcn_s_setprio(1);
      #pragma unroll
      for (int i = 0; i < 4; ++i) {
        bf16x8 af = *(const bf16x8*)&Ab[(i * 16 + l15) * 256 + (((ks * 4 + lg) ^ (l15 & 7)) * 8)];
        #pragma unroll
        for (int j = 0; j < 4; ++j)
          acc[i][j] = __builtin_amdgcn_mfma_f32_16x16x32_bf16(af, bgc[j], acc[i][j], 0, 0, 0);
      }
      __builtin_amdgcn_s_setprio(0);
    }

    // ---- epilogue: sq = z2 + p2 - 2*dot (clamped), row/col mins ----
    #pragma unroll
    for (int i = 0; i < 4; ++i) {
      #pragma unroll
      for (int r = 0; r < 4; ++r) {
        int arow = i * 16 + lg * 4 + r;     // C layout: col=lane&15, row=(lane>>4)*4+r
        float z2 = z2s[cur][arow];
        float m = 3.4e38f;
        #pragma unroll
        for (int j = 0; j < 4; ++j) {
          float sq = fmaxf(z2 + p2r[j] - 2.0f * acc[i][j][r], 0.0f);
          m = fminf(m, sq);
          colmin[j] = fminf(colmin[j], sq);
        }
        m = fminf(m, __shfl_xor(m, 1));
        m = fminf(m, __shfl_xor(m, 2));
        m = fminf(m, __shfl_xor(m, 4));
        m = fminf(m, __shfl_xor(m, 8));
        if (l15 == 0) rowred[arow * 4 + w] = m;
      }
    }
    __syncthreads();  // rowred visible; buf[nxt] reads (tile tt-1) long done

    if (t < 64) {
      float m = fminf(fminf(rowred[t * 4], rowred[t * 4 + 1]),
                      fminf(rowred[t * 4 + 2], rowred[t * 4 + 3]));
      rowminpart[(size_t)cc * N_ROWS + row0 + t] = m;  // coalesced 64 floats
    }

    // ---- convert staged regs -> buf[nxt] for tile tt+1 ----
    if (tt < TPB - 1) {
      unsigned short* An = cur ? A0 : A1;
      float zacc = 0.f;
      #pragma unroll
      for (int m = 0; m < 8; ++m) {
        float4 a0 = za[2 * m], a1 = za[2 * m + 1];
        zacc += a0.x*a0.x + a0.y*a0.y + a0.z*a0.z + a0.w*a0.w
              + a1.x*a1.x + a1.y*a1.y + a1.z*a1.z + a1.w*a1.w;
        bf16x8 pk;
        pk[0] = (__bf16)a0.x; pk[1] = (__bf16)a0.y; pk[2] = (__bf16)a0.z; pk[3] = (__bf16)a0.w;
        pk[4] = (__bf16)a1.x; pk[5] = (__bf16)a1.y; pk[6] = (__bf16)a1.z; pk[7] = (__bf16)a1.w;
        int slot = (sc4 + m * 4) ^ (srow & 7);
        *(bf16x8*)&An[srow * 256 + slot * 8] = pk;
      }
      zacc += __shfl_xor(zacc, 1);
      zacc += __shfl_xor(zacc, 2);
      if (sc4 == 0) z2s[cur ^ 1][srow] = zacc;
    }
    __syncthreads();  // LDS ready for tt+1; rowred reads done before next write
  }

  // ---- block col-min outputs (accumulated over all 8 tiles) ----
  if (l < 16) {
    #pragma unroll
    for (int j = 0; j < 4; ++j)
      colpart[(size_t)rg * PROTO + cc * 256 + w * 64 + j * 16 + l] = colmin[j];
  }
}

// ---------------- col reduce: min over 512 rg-partials per col, sqrt ----------------
// 32 blocks x 512 threads; block handles 16 cols. col = t&15, g-group = t>>4.
__global__ void col_reduce(const float* __restrict__ colpart, float* __restrict__ colfin) {
  int t    = threadIdx.x;          // 512
  int colb = blockIdx.x * 16;      // 32 blocks
  int cl   = t & 15;
  int gg   = t >> 4;               // 0..31
  float m = 3.4e38f;
  for (int g = gg; g < RGS; g += 32)
    m = fminf(m, colpart[(size_t)g * PROTO + colb + cl]);
  m = fminf(m, __shfl_xor(m, 16));
  m = fminf(m, __shfl_xor(m, 32));
  __shared__ float red[8][16];
  if ((t & 63) < 16) red[t >> 6][cl] = m;
  __syncthreads();
  if (t < 16) {
    float r = red[0][t];
    #pragma unroll
    for (int wv = 1; wv < 8; ++wv) r = fminf(r, red[wv][t]);
    colfin[colb + t] = sqrtf(r);
  }
}

// ---------------- row reduce: min over 2 col-chunk partials, sqrt, block sum ----------------
__global__ void row_reduce(const float* __restrict__ rowminpart, float* __restrict__ rowsum) {
  int t = threadIdx.x;                         // 256
  size_t grow = (size_t)blockIdx.x * 256 + t;  // 1024 blocks
  float m = fminf(rowminpart[grow], rowminpart[N_ROWS + grow]);
  float s = sqrtf(m);
  #pragma unroll
  for (int mm = 1; mm < 64; mm <<= 1) s += __shfl_xor(s, mm);
  __shared__ float ws4[4];
  if ((t & 63) == 0) ws4[t >> 6] = s;
  __syncthreads();
  if (t == 0) rowsum[blockIdx.x] = (ws4[0] + ws4[1]) + (ws4[2] + ws4[3]);
}

// ---------------- final combine ----------------
__global__ void final_reduce(const float* __restrict__ colfin,
                             const float* __restrict__ rowsum,
                             float* __restrict__ out) {
  int t = threadIdx.x;   // 512
  float sc = colfin[t];
  float sr = rowsum[t] + rowsum[t + 512];
  #pragma unroll
  for (int mm = 1; mm < 64; mm <<= 1) { sc += __shfl_xor(sc, mm); sr += __shfl_xor(sr, mm); }
  __shared__ float wc[8], wr[8];
  if ((t & 63) == 0) { wc[t >> 6] = sc; wr[t >> 6] = sr; }
  __syncthreads();
  if (t == 0) {
    float tc = 0.f, tr = 0.f;
    #pragma unroll
    for (int i = 0; i < 8; ++i) { tc += wc[i]; tr += wr[i]; }
    out[0] = 0.05f * (tr / (float)N_ROWS) + 0.05f * (tc / (float)PROTO);
  }
}

extern "C" void kernel_launch(void* const* d_in, const int* in_sizes, int n_in,
                              void* d_out, int out_size, void* d_ws, size_t ws_size,
                              hipStream_t stream) {
  const float* z  = (const float*)d_in[0];
  const float* pv = (const float*)d_in[1];
  char* ws = (char*)d_ws;
  size_t off = 0;
  unsigned short* PBf = (unsigned short*)(ws + off); off += 262144;               // 256 KB
  float* P2           = (float*)(ws + off);          off += 2048;
  float* colpart      = (float*)(ws + off);          off += (size_t)RGS * PROTO * 4;  // 1 MB
  float* colfin       = (float*)(ws + off);          off += 2048;
  float* rowminpart   = (float*)(ws + off);          off += (size_t)2 * N_ROWS * 4;   // 2 MB
  float* rowsum       = (float*)(ws + off);          off += 4096;

  prep_proto<<<PROTO, DDIM, 0, stream>>>(pv, PBf, P2);
  proto_main<<<NBLK, 256, 0, stream>>>(z, PBf, P2, colpart, rowminpart);
  col_reduce<<<32, 512, 0, stream>>>(colpart, colfin);
  row_reduce<<<N_ROWS / 256, 256, 0, stream>>>(rowminpart, rowsum);
  final_reduce<<<1, PROTO, 0, stream>>>(colfin, rowsum, (float*)d_out);
}

// Round 13
// 139.408 us; speedup vs baseline: 3.4943x; 3.4943x over previous
//
#include <hip/hip_runtime.h>
#include <hip/hip_bf16.h>

#define N_ROWS 262144
#define DDIM   256
#define PROTO  512
#define BM     64
#define RTG    4096   // row tiles
#define NBLK   8192   // RTG * 2 col-chunks

typedef __bf16 bf16x8 __attribute__((ext_vector_type(8)));
typedef float  f32x4  __attribute__((ext_vector_type(4)));

// ---------------- prep: prototypes fp32 -> bf16 in MFMA-fragment order, p2 ----------------
// idx = (p>>4)*4096 + (k>>5)*512 + ((((k>>3)&3)*16) + (p&15))*8 + (k&7)
__global__ void prep_proto(const float* __restrict__ Pm,
                           unsigned short* __restrict__ PBf,
                           float* __restrict__ P2) {
  int p = blockIdx.x;     // 512
  int k = threadIdx.x;    // 256
  float v = Pm[p * DDIM + k];
  int idx = (p >> 4) * 4096 + (k >> 5) * 512 + ((((k >> 3) & 3) * 16) + (p & 15)) * 8 + (k & 7);
  ((__bf16*)PBf)[idx] = (__bf16)v;
  float sq = v * v;
  #pragma unroll
  for (int m = 1; m < 64; m <<= 1) sq += __shfl_xor(sq, m);
  __shared__ float ws4[4];
  if ((k & 63) == 0) ws4[k >> 6] = sq;
  __syncthreads();
  if (k == 0) P2[p] = (ws4[0] + ws4[1]) + (ws4[2] + ws4[3]);
}

// ---------------- main: fused GEMM + row/col min, ONE 64-row tile per block ----------------
// 8192 blocks x 256 threads; __launch_bounds__(256,4) -> 128 regs/wave -> 4 blocks/CU.
// g = ((bid>>4)<<3)|(bid&7), cc = (bid>>3)&1: siblings share an XCD (Z tile L2-shared).
// A tile: linear [64][256] bf16 LDS with 16B-slot XOR swizzle slot' = slot ^ (row&7).
// B streams from L2-hot fragment-ordered PBf with a 1-deep double-buffer (bgn/bgc).
__global__ __launch_bounds__(256, 4)
void proto_main(const float* __restrict__ Z, const unsigned short* __restrict__ PBf,
                const float* __restrict__ P2, float* __restrict__ colpart,
                float* __restrict__ rowminpart) {
  __shared__ __align__(16) unsigned short A_lds[BM * 256];  // 32768 B, swizzled
  __shared__ float z2s[BM];
  __shared__ float rowred[BM * 4];

  const int t   = threadIdx.x;
  const int w   = t >> 6;   // wave 0..3
  const int l   = t & 63;
  const int l15 = l & 15;
  const int lg  = l >> 4;   // 0..3

  const int bid = blockIdx.x;
  const int g   = ((bid >> 4) << 3) | (bid & 7);  // row tile 0..4095
  const int cc  = (bid >> 3) & 1;                 // col chunk 0..1
  const size_t row0 = (size_t)g * BM;

  // ---- stage A tile (64 x 256): float4 loads -> bf16 swizzled LDS + fp32 z2 ----
  const int srow = t >> 2;  // 4 threads per row
  const int sc4  = t & 3;
  {
    const float4* Zv = (const float4*)Z + (row0 + srow) * (DDIM / 4);
    float zacc = 0.f;
    #pragma unroll
    for (int m = 0; m < 8; ++m) {
      float4 a0 = Zv[(sc4 + m * 4) * 2];
      float4 a1 = Zv[(sc4 + m * 4) * 2 + 1];
      zacc += a0.x*a0.x + a0.y*a0.y + a0.z*a0.z + a0.w*a0.w
            + a1.x*a1.x + a1.y*a1.y + a1.z*a1.z + a1.w*a1.w;
      bf16x8 pk;
      pk[0] = (__bf16)a0.x; pk[1] = (__bf16)a0.y; pk[2] = (__bf16)a0.z; pk[3] = (__bf16)a0.w;
      pk[4] = (__bf16)a1.x; pk[5] = (__bf16)a1.y; pk[6] = (__bf16)a1.z; pk[7] = (__bf16)a1.w;
      int slot = (sc4 + m * 4) ^ (srow & 7);       // 16B-slot XOR swizzle
      *(bf16x8*)&A_lds[srow * 256 + slot * 8] = pk;
    }
    zacc += __shfl_xor(zacc, 1);
    zacc += __shfl_xor(zacc, 2);
    if (sc4 == 0) z2s[srow] = zacc;
  }

  float p2r[4];
  #pragma unroll
  for (int j = 0; j < 4; ++j) p2r[j] = P2[cc * 256 + w * 64 + j * 16 + l15];

  __syncthreads();  // A_lds + z2s visible

  f32x4 acc[4][4];
  #pragma unroll
  for (int i = 0; i < 4; ++i)
    #pragma unroll
    for (int j = 0; j < 4; ++j)
      acc[i][j] = (f32x4){0.f, 0.f, 0.f, 0.f};

  // ---- K loop: 8 steps of BK=32; A from swizzled LDS, B double-buffered from L2 ----
  const unsigned short* PBw = PBf + (size_t)(cc * 16 + w * 4) * 4096 + l * 8;
  bf16x8 bgn[4];
  #pragma unroll
  for (int j = 0; j < 4; ++j)
    bgn[j] = *(const bf16x8*)&PBw[(size_t)(j * 8) * 512];
  #pragma unroll
  for (int ks = 0; ks < 8; ++ks) {
    bf16x8 bgc[4];
    #pragma unroll
    for (int j = 0; j < 4; ++j) bgc[j] = bgn[j];
    if (ks < 7) {
      #pragma unroll
      for (int j = 0; j < 4; ++j)
        bgn[j] = *(const bf16x8*)&PBw[(size_t)(j * 8 + ks + 1) * 512];
    }
    __builtin_amdgcn_s_setprio(1);
    #pragma unroll
    for (int i = 0; i < 4; ++i) {
      bf16x8 af = *(const bf16x8*)&A_lds[(i * 16 + l15) * 256 + (((ks * 4 + lg) ^ (l15 & 7)) * 8)];
      #pragma unroll
      for (int j = 0; j < 4; ++j)
        acc[i][j] = __builtin_amdgcn_mfma_f32_16x16x32_bf16(af, bgc[j], acc[i][j], 0, 0, 0);
    }
    __builtin_amdgcn_s_setprio(0);
  }

  // ---- epilogue: sq = z2 + p2 - 2*dot (clamped), row/col mins ----
  float cmin[4] = {3.4e38f, 3.4e38f, 3.4e38f, 3.4e38f};
  #pragma unroll
  for (int i = 0; i < 4; ++i) {
    #pragma unroll
    for (int r = 0; r < 4; ++r) {
      int arow = i * 16 + lg * 4 + r;     // C layout: col=lane&15, row=(lane>>4)*4+r
      float z2 = z2s[arow];
      float m = 3.4e38f;
      #pragma unroll
      for (int j = 0; j < 4; ++j) {
        float sq = fmaxf(z2 + p2r[j] - 2.0f * acc[i][j][r], 0.0f);
        m = fminf(m, sq);
        cmin[j] = fminf(cmin[j], sq);
      }
      m = fminf(m, __shfl_xor(m, 1));
      m = fminf(m, __shfl_xor(m, 2));
      m = fminf(m, __shfl_xor(m, 4));
      m = fminf(m, __shfl_xor(m, 8));
      if (l15 == 0) rowred[arow * 4 + w] = m;
    }
  }
  // col-min across row-groups -> plain per-block stores (deterministic, no atomics)
  #pragma unroll
  for (int j = 0; j < 4; ++j) {
    float c = cmin[j];
    c = fminf(c, __shfl_xor(c, 16));
    c = fminf(c, __shfl_xor(c, 32));
    cmin[j] = c;
  }
  if (l < 16) {
    #pragma unroll
    for (int j = 0; j < 4; ++j)
      colpart[(size_t)g * PROTO + cc * 256 + w * 64 + j * 16 + l] = cmin[j];
  }
  __syncthreads();  // rowred visible
  if (t < 64) {
    float m = fminf(fminf(rowred[t * 4], rowred[t * 4 + 1]),
                    fminf(rowred[t * 4 + 2], rowred[t * 4 + 3]));
    rowminpart[(size_t)cc * N_ROWS + row0 + t] = m;  // coalesced 64 floats
  }
}

// ---------------- col reduce: min over 4096 g-partials per col, sqrt ----------------
__global__ void col_reduce(const float* __restrict__ colpart, float* __restrict__ colfin) {
  int t    = threadIdx.x;          // 512
  int colb = blockIdx.x * 16;      // 32 blocks
  int cl   = t & 15;
  int gg   = t >> 4;               // 0..31
  float m = 3.4e38f;
  for (int g = gg; g < RTG; g += 32)
    m = fminf(m, colpart[(size_t)g * PROTO + colb + cl]);
  m = fminf(m, __shfl_xor(m, 16));
  m = fminf(m, __shfl_xor(m, 32));
  __shared__ float red[8][16];
  if ((t & 63) < 16) red[t >> 6][cl] = m;
  __syncthreads();
  if (t < 16) {
    float r = red[0][t];
    #pragma unroll
    for (int wv = 1; wv < 8; ++wv) r = fminf(r, red[wv][t]);
    colfin[colb + t] = sqrtf(r);
  }
}

// ---------------- row reduce: min over 2 col-chunk partials, sqrt, block sum ----------------
__global__ void row_reduce(const float* __restrict__ rowminpart, float* __restrict__ rowsum) {
  int t = threadIdx.x;                         // 256
  size_t grow = (size_t)blockIdx.x * 256 + t;  // 1024 blocks
  float m = fminf(rowminpart[grow], rowminpart[N_ROWS + grow]);
  float s = sqrtf(m);
  #pragma unroll
  for (int mm = 1; mm < 64; mm <<= 1) s += __shfl_xor(s, mm);
  __shared__ float ws4[4];
  if ((t & 63) == 0) ws4[t >> 6] = s;
  __syncthreads();
  if (t == 0) rowsum[blockIdx.x] = (ws4[0] + ws4[1]) + (ws4[2] + ws4[3]);
}

// ---------------- final combine ----------------
__global__ void final_reduce(const float* __restrict__ colfin,
                             const float* __restrict__ rowsum,
                             float* __restrict__ out) {
  int t = threadIdx.x;   // 512
  float sc = colfin[t];
  float sr = rowsum[t] + rowsum[t + 512];
  #pragma unroll
  for (int mm = 1; mm < 64; mm <<= 1) { sc += __shfl_xor(sc, mm); sr += __shfl_xor(sr, mm); }
  __shared__ float wc[8], wr[8];
  if ((t & 63) == 0) { wc[t >> 6] = sc; wr[t >> 6] = sr; }
  __syncthreads();
  if (t == 0) {
    float tc = 0.f, tr = 0.f;
    #pragma unroll
    for (int i = 0; i < 8; ++i) { tc += wc[i]; tr += wr[i]; }
    out[0] = 0.05f * (tr / (float)N_ROWS) + 0.05f * (tc / (float)PROTO);
  }
}

extern "C" void kernel_launch(void* const* d_in, const int* in_sizes, int n_in,
                              void* d_out, int out_size, void* d_ws, size_t ws_size,
                              hipStream_t stream) {
  const float* z  = (const float*)d_in[0];
  const float* pv = (const float*)d_in[1];
  char* ws = (char*)d_ws;
  size_t off = 0;
  unsigned short* PBf = (unsigned short*)(ws + off); off += 262144;               // 256 KB
  float* P2           = (float*)(ws + off);          off += 2048;
  float* colpart      = (float*)(ws + off);          off += (size_t)RTG * PROTO * 4;  // 8 MB
  float* colfin       = (float*)(ws + off);          off += 2048;
  float* rowminpart   = (float*)(ws + off);          off += (size_t)2 * N_ROWS * 4;   // 2 MB
  float* rowsum       = (float*)(ws + off);          off += 4096;

  prep_proto<<<PROTO, DDIM, 0, stream>>>(pv, PBf, P2);
  proto_main<<<NBLK, 256, 0, stream>>>(z, PBf, P2, colpart, rowminpart);
  col_reduce<<<32, 512, 0, stream>>>(colpart, colfin);
  row_reduce<<<N_ROWS / 256, 256, 0, stream>>>(rowminpart, rowsum);
  final_reduce<<<1, PROTO, 0, stream>>>(colfin, rowsum, (float*)d_out);
}